// Round 19
// baseline (118.926 us; speedup 1.0000x reference)
//
#include <hip/hip_runtime.h>
#include <math.h>

#define BB 8
#define NN 4096
#define MM 4000
#define KK 5
#define NWAVE 8
#define QG 256                        // queries per block (4 per lane)
#define CH 256                        // candidates per wave-chunk per half
#define HSZ 2048                      // candidates staged per half
#define NPAD 4096
#define SCAN_BLOCKS ((NN / QG) * BB * 2)   // 16*8*2 = 256

#define ACC_ROT    0
#define ACC_TRANS  1
#define ACC_ALIGN  2
#define ACC_DISP   3
#define ACC_DEFORM 4
#define ACC_LAP    5
#define ACC_RMSE   6   // 8 entries
#define ACC_COUNT  14

#define INFF __int_as_float(0x7F800000)

struct Chain { float b0, b1, b2, b3, b4; };   // static-member access only (no scratch)

__device__ __forceinline__ float waveReduceSum(float v) {
#pragma unroll
    for (int off = 32; off > 0; off >>= 1) v += __shfl_down(v, off, 64);
    return v;
}

// Insert v into sorted chain: 1 min + 4 independent med3 (proven r6+). Score
// shifted by -|q|^2 (ranking-invariant). PACK: candidate index in low 12
// mantissa bits (tie -> smaller index, = top_k semantics).
template<bool SELF, bool PACK>
__device__ __forceinline__ void proc1(float4 c, int midx, int q,
                                      float ca, float cbq, float cc, Chain& h) {
    float sc = fmaf(c.x, ca, fmaf(c.y, cbq, fmaf(c.z, cc, c.w)));
    float v;
    if (PACK) {
        unsigned pk = (__float_as_uint(sc) & 0xFFFFF000u) | (unsigned)midx;
        v = __uint_as_float(pk);
        if (SELF) v = (midx == q) ? INFF : v;
    } else {
        v = sc;
    }
    float n0 = fminf(h.b0, v);
    float n1 = __builtin_amdgcn_fmed3f(v, h.b0, h.b1);
    float n2 = __builtin_amdgcn_fmed3f(v, h.b1, h.b2);
    float n3 = __builtin_amdgcn_fmed3f(v, h.b2, h.b3);
    float n4 = __builtin_amdgcn_fmed3f(v, h.b3, h.b4);
    h.b0 = n0; h.b1 = n1; h.b2 = n2; h.b3 = n3; h.b4 = n4;
}

// Scan a CH-candidate LDS chunk for FOUR queries per lane: one broadcast
// ds_read_b128 serves 256 pairs (DS ops halved vs Q=2), and 4 independent
// insert chains give 20 in-flight VALU ops -> issue stays fed at 2 waves/SIMD.
template<bool SELF, bool PACK>
__device__ __forceinline__ void scanLDS4(const float4* lc, int tl, int tg,
                                         float a0, float e0, float c0, int q0, Chain& C0,
                                         float a1, float e1, float c1, int q1, Chain& C1,
                                         float a2, float e2, float c2, int q2, Chain& C2,
                                         float a3, float e3, float c3, int q3, Chain& C3) {
    float4 A[4], B[4];
#pragma unroll
    for (int j = 0; j < 4; ++j) A[j] = lc[tl + j];

    for (int t0 = 0; t0 < CH; t0 += 8) {
#pragma unroll
        for (int j = 0; j < 4; ++j) B[j] = lc[tl + t0 + 4 + j];
#pragma unroll
        for (int j = 0; j < 4; ++j) {
            int m = tg + t0 + j;
            proc1<SELF, PACK>(A[j], m, q0, a0, e0, c0, C0);
            proc1<SELF, PACK>(A[j], m, q1, a1, e1, c1, C1);
            proc1<SELF, PACK>(A[j], m, q2, a2, e2, c2, C2);
            proc1<SELF, PACK>(A[j], m, q3, a3, e3, c3, C3);
        }
        if (t0 + 8 < CH) {
#pragma unroll
            for (int j = 0; j < 4; ++j) A[j] = lc[tl + t0 + 8 + j];
        }
#pragma unroll
        for (int j = 0; j < 4; ++j) {
            int m = tg + t0 + 4 + j;
            proc1<SELF, PACK>(B[j], m, q0, a0, e0, c0, C0);
            proc1<SELF, PACK>(B[j], m, q1, a1, e1, c1, C1);
            proc1<SELF, PACK>(B[j], m, q2, a2, e2, c2, C2);
            proc1<SELF, PACK>(B[j], m, q3, a3, e3, c3, C3);
        }
    }
}

// Merge two sorted 5-lists -> smallest 5 ascending, fully static min/max
// network (r14-proven bit-exact).
__device__ __forceinline__ void merge5(float& a0, float& a1, float& a2,
                                       float& a3, float& a4,
                                       float m0, float m1, float m2,
                                       float m3, float m4) {
    float u0 = fminf(a0, m0);
    float u1 = fminf(fminf(a1, m1), fmaxf(a0, m0));
    float u2 = fminf(fminf(a2, m2), fminf(fmaxf(a0, m1), fmaxf(a1, m0)));
    float u3 = fminf(fminf(a3, m3),
                     fminf(fmaxf(a0, m2), fminf(fmaxf(a1, m1), fmaxf(a2, m0))));
    float u4 = fminf(fminf(a4, m4),
                     fminf(fminf(fmaxf(a0, m3), fmaxf(a1, m2)),
                           fminf(fmaxf(a2, m1), fmaxf(a3, m0))));
    a0 = u0; a1 = u1; a2 = u2; a3 = u3; a4 = u4;
}

// K1: Y_rigid (padded float4 + norm), X padded float4 + norm, rmse/disp
// partials, rot/trans losses.
__global__ void k_prep(const float* __restrict__ Y, const float* __restrict__ X,
                       const float* __restrict__ Rp, const float* __restrict__ tp,
                       const float* __restrict__ Rg, const float* __restrict__ tg,
                       const float* __restrict__ dl,
                       float4* __restrict__ YrP, float4* __restrict__ XP,
                       float* __restrict__ acc) {
    int b = blockIdx.x >> 4;
    int n = ((blockIdx.x & 15) << 8) + threadIdx.x;
    size_t base = ((size_t)b * NN + n) * 3;
    float yx = Y[base + 0], yy = Y[base + 1], yz = Y[base + 2];

    float rp[9], rg[9], tpv[3], tgv[3];
#pragma unroll
    for (int i = 0; i < 9; ++i) { rp[i] = Rp[b * 9 + i]; rg[i] = Rg[b * 9 + i]; }
#pragma unroll
    for (int i = 0; i < 3; ++i) { tpv[i] = tp[b * 3 + i]; tgv[i] = tg[b * 3 + i]; }

    float p[3], dr2 = 0.f;
#pragma unroll
    for (int k = 0; k < 3; ++k) {
        float pv = fmaf(yx, rp[k * 3 + 0], fmaf(yy, rp[k * 3 + 1], fmaf(yz, rp[k * 3 + 2], tpv[k])));
        float gv = fmaf(yx, rg[k * 3 + 0], fmaf(yy, rg[k * 3 + 1], fmaf(yz, rg[k * 3 + 2], tgv[k])));
        p[k] = pv;
        float dd = pv - gv;
        dr2 = fmaf(dd, dd, dr2);
    }
    YrP[(size_t)b * NPAD + n] =
        make_float4(p[0], p[1], p[2], fmaf(p[0], p[0], fmaf(p[1], p[1], p[2] * p[2])));

    float4 xe;
    if (n < MM) {
        size_t xb = ((size_t)b * MM + n) * 3;
        float x0 = X[xb + 0], x1 = X[xb + 1], x2 = X[xb + 2];
        xe = make_float4(x0, x1, x2, fmaf(x0, x0, fmaf(x1, x1, x2 * x2)));
    } else {
        xe = make_float4(0.f, 0.f, 0.f, INFF);
    }
    XP[(size_t)b * NPAD + n] = xe;

    float d0 = dl[base + 0], d1 = dl[base + 1], d2 = dl[base + 2];
    float dsq = d0 * d0 + d1 * d1 + d2 * d2;

    dr2 = waveReduceSum(dr2);
    dsq = waveReduceSum(dsq);
    if ((threadIdx.x & 63) == 0) {
        atomicAdd(&acc[ACC_RMSE + b], dr2);
        atomicAdd(&acc[ACC_DISP], dsq);
    }

    if (threadIdx.x == 0 && (blockIdx.x & 15) == 0) {
        float tr = 0.f;
#pragma unroll
        for (int i = 0; i < 9; ++i) tr += rp[i] * rg[i];
        float c = (tr - 1.f) * 0.5f;
        c = fminf(fmaxf(c, -1.f + 1e-7f), 1.f - 1e-7f);
        float dx = tpv[0] - tgv[0], dy = tpv[1] - tgv[1], dz = tpv[2] - tgv[2];
        atomicAdd(&acc[ACC_ROT], acosf(c));
        atomicAdd(&acc[ACC_TRANS], sqrtf(dx * dx + dy * dy + dz * dz));
    }
}

__device__ void finalize(const float* acc, float* out) {
    float a[ACC_COUNT];
#pragma unroll
    for (int i = 0; i < ACC_COUNT; ++i)
        a[i] = __hip_atomic_load(&acc[i], __ATOMIC_RELAXED, __HIP_MEMORY_SCOPE_AGENT);
    float L_rot = a[ACC_ROT] / BB;
    float L_trans = a[ACC_TRANS] / BB;
    float L_rmse = 0.f;
#pragma unroll
    for (int b = 0; b < BB; ++b) L_rmse += sqrtf(a[ACC_RMSE + b] / NN);
    L_rmse /= BB;
    float L_align = a[ACC_ALIGN] / ((float)BB * NN * KK);
    float L_disp = a[ACC_DISP] / ((float)BB * NN);
    float L_def = a[ACC_DEFORM] / ((float)BB * NN * KK);
    float L_lap = a[ACC_LAP] / ((float)BB * NN);
    float rigid = L_rot + L_trans + L_rmse;
    float nr = L_align + 0.01f * L_disp + 0.1f * L_def + 0.1f * L_lap;
    out[0] = rigid + nr; out[1] = rigid; out[2] = nr;
    out[3] = L_rot; out[4] = L_trans; out[5] = L_rmse;
    out[6] = L_align; out[7] = L_disp; out[8] = L_def; out[9] = L_lap;
}

#define MERGE_STEP(W) { float d = md[W][l][pp##W]; if (d < best) { best = d; bw = W; } }
#define MERGE_ADV()  { pp0 += (bw == 0); pp1 += (bw == 1); pp2 += (bw == 2); pp3 += (bw == 3); \
                       pp4 += (bw == 4); pp5 += (bw == 5); pp6 += (bw == 6); pp7 += (bw == 7); }

// K2: fused scan, Q=4/lane (QG=256). blockIdx.z = mode. Loop over 2 halves:
// stage 2048 cands (32 KB), 8 waves x 256-chunks x 4 chains; per-half 8-way
// LDS merge (md 48 KB, separate) -> static merge5 in registers; epilogue +
// last-block finalize in-block. 80 KB LDS, 256 blocks (1/CU).
__global__ __launch_bounds__(512, 4) void k_scan(const float* __restrict__ Xh,
                                                 const float4* __restrict__ XP,
                                                 const float4* __restrict__ YrP,
                                                 const float* __restrict__ dl,
                                                 float* __restrict__ acc,
                                                 unsigned* __restrict__ doneCnt,
                                                 float* __restrict__ out) {
    __shared__ float4 stage[HSZ];                  // 32 KB candidate stage
    __shared__ float md[NWAVE][QG][6];             // 48 KB merge partials
    int tid = threadIdx.x, wave = tid >> 6, lane = tid & 63;
    int qg = blockIdx.x, b = blockIdx.y, mode = blockIdx.z;
    int q0 = qg * QG + lane, q1 = q0 + 64, q2 = q0 + 128, q3 = q0 + 192;

    const float4* cbG = (mode == 0 ? XP : YrP) + (size_t)b * NPAD;

    float ax0, ay0, az0, ax1, ay1, az1, ax2, ay2, az2, ax3, ay3, az3;
    if (mode == 0) {
        size_t a0 = ((size_t)b * NN + q0) * 3;
        size_t a1 = ((size_t)b * NN + q1) * 3;
        size_t a2 = ((size_t)b * NN + q2) * 3;
        size_t a3 = ((size_t)b * NN + q3) * 3;
        ax0 = Xh[a0 + 0]; ay0 = Xh[a0 + 1]; az0 = Xh[a0 + 2];
        ax1 = Xh[a1 + 0]; ay1 = Xh[a1 + 1]; az1 = Xh[a1 + 2];
        ax2 = Xh[a2 + 0]; ay2 = Xh[a2 + 1]; az2 = Xh[a2 + 2];
        ax3 = Xh[a3 + 0]; ay3 = Xh[a3 + 1]; az3 = Xh[a3 + 2];
    } else {
        float4 p0 = cbG[q0], p1 = cbG[q1], p2 = cbG[q2], p3 = cbG[q3];
        ax0 = p0.x; ay0 = p0.y; az0 = p0.z;
        ax1 = p1.x; ay1 = p1.y; az1 = p1.z;
        ax2 = p2.x; ay2 = p2.y; az2 = p2.z;
        ax3 = p3.x; ay3 = p3.y; az3 = p3.z;
    }

    float f0 = INFF, f1 = INFF, f2 = INFF, f3 = INFF, f4 = INFF;  // running top-5 (merge thread)

#pragma unroll
    for (int half = 0; half < 2; ++half) {
        __syncthreads();                           // prev-half merge reads of md done
#pragma unroll
        for (int i = 0; i < HSZ / 512; ++i)
            stage[tid + i * 512] = cbG[half * HSZ + tid + i * 512];
        __syncthreads();

        Chain C0 = { INFF, INFF, INFF, INFF, INFF };
        Chain C1 = { INFF, INFF, INFF, INFF, INFF };
        Chain C2 = { INFF, INFF, INFF, INFF, INFF };
        Chain C3 = { INFF, INFF, INFF, INFF, INFF };
        int tl = wave * CH;
        int tg = half * HSZ + tl;
        // the block's 256 queries == candidate chunk qg: half qg>>3, wave qg&7
        bool hasSelf = (mode == 1) && (half == (qg >> 3)) && (wave == (qg & 7));
        if (mode == 0) {
            scanLDS4<false, false>(stage, tl, tg,
                                   -2.f * ax0, -2.f * ay0, -2.f * az0, 0, C0,
                                   -2.f * ax1, -2.f * ay1, -2.f * az1, 0, C1,
                                   -2.f * ax2, -2.f * ay2, -2.f * az2, 0, C2,
                                   -2.f * ax3, -2.f * ay3, -2.f * az3, 0, C3);
        } else if (hasSelf) {
            scanLDS4<true, true>(stage, tl, tg,
                                 -2.f * ax0, -2.f * ay0, -2.f * az0, q0, C0,
                                 -2.f * ax1, -2.f * ay1, -2.f * az1, q1, C1,
                                 -2.f * ax2, -2.f * ay2, -2.f * az2, q2, C2,
                                 -2.f * ax3, -2.f * ay3, -2.f * az3, q3, C3);
        } else {
            scanLDS4<false, true>(stage, tl, tg,
                                  -2.f * ax0, -2.f * ay0, -2.f * az0, q0, C0,
                                  -2.f * ax1, -2.f * ay1, -2.f * az1, q1, C1,
                                  -2.f * ax2, -2.f * ay2, -2.f * az2, q2, C2,
                                  -2.f * ax3, -2.f * ay3, -2.f * az3, q3, C3);
        }

        float* m;
        m = &md[wave][lane][0];
        m[0] = C0.b0; m[1] = C0.b1; m[2] = C0.b2; m[3] = C0.b3; m[4] = C0.b4; m[5] = INFF;
        m = &md[wave][lane + 64][0];
        m[0] = C1.b0; m[1] = C1.b1; m[2] = C1.b2; m[3] = C1.b3; m[4] = C1.b4; m[5] = INFF;
        m = &md[wave][lane + 128][0];
        m[0] = C2.b0; m[1] = C2.b1; m[2] = C2.b2; m[3] = C2.b3; m[4] = C2.b4; m[5] = INFF;
        m = &md[wave][lane + 192][0];
        m[0] = C3.b0; m[1] = C3.b1; m[2] = C3.b2; m[3] = C3.b3; m[4] = C3.b4; m[5] = INFF;
        __syncthreads();

        if (tid < QG) {
            int l = tid;
            int pp0 = 0, pp1 = 0, pp2 = 0, pp3 = 0, pp4 = 0, pp5 = 0, pp6 = 0, pp7 = 0;
            float m5[KK];
#pragma unroll
            for (int k = 0; k < KK; ++k) {
                float best = INFF; int bw = 0;
                MERGE_STEP(0) MERGE_STEP(1) MERGE_STEP(2) MERGE_STEP(3)
                MERGE_STEP(4) MERGE_STEP(5) MERGE_STEP(6) MERGE_STEP(7)
                m5[k] = best;
                MERGE_ADV()
            }
            merge5(f0, f1, f2, f3, f4, m5[0], m5[1], m5[2], m5[3], m5[4]);
        }
    }

    // ---- epilogue (tid < QG owns query q) ----
    if (tid < QG) {
        int l = tid;
        int q = qg * QG + l;
        if (mode == 0) {
            size_t a0 = ((size_t)b * NN + q) * 3;
            float qx = Xh[a0 + 0], qy = Xh[a0 + 1], qz = Xh[a0 + 2];
            float qn = fmaf(qx, qx, fmaf(qy, qy, qz * qz));
            float s = fmaxf(f0 + qn, 0.f) + fmaxf(f1 + qn, 0.f) + fmaxf(f2 + qn, 0.f)
                    + fmaxf(f3 + qn, 0.f) + fmaxf(f4 + qn, 0.f);
            s = waveReduceSum(s);
            if ((l & 63) == 0) atomicAdd(&acc[ACC_ALIGN], s);
        } else {
            int si[KK];
            si[0] = (int)(__float_as_uint(f0) & 0xFFFu);
            si[1] = (int)(__float_as_uint(f1) & 0xFFFu);
            si[2] = (int)(__float_as_uint(f2) & 0xFFFu);
            si[3] = (int)(__float_as_uint(f3) & 0xFFFu);
            si[4] = (int)(__float_as_uint(f4) & 0xFFFu);

            float4 qp = cbG[q];
            const float* xh = Xh + (size_t)b * NN * 3;
            const float* dlb = dl + (size_t)b * NN * 3;
            float xnx = xh[q * 3 + 0], xny = xh[q * 3 + 1], xnz = xh[q * 3 + 2];
            float dnx = dlb[q * 3 + 0], dny = dlb[q * 3 + 1], dnz = dlb[q * 3 + 2];

            float def = 0.f, sx = 0.f, sy = 0.f, sz = 0.f;
#pragma unroll
            for (int k = 0; k < KK; ++k) {
                int n = si[k];
                float4 yj = cbG[n];                // L2-resident gather
                float ex = (xh[n * 3 + 0] - xnx) - (yj.x - qp.x);
                float ey = (xh[n * 3 + 1] - xny) - (yj.y - qp.y);
                float ez = (xh[n * 3 + 2] - xnz) - (yj.z - qp.z);
                def += ex * ex + ey * ey + ez * ez;
                sx += dlb[n * 3 + 0]; sy += dlb[n * 3 + 1]; sz += dlb[n * 3 + 2];
            }
            float lx = dnx - sx / 5.f, ly = dny - sy / 5.f, lz = dnz - sz / 5.f;
            float lap = lx * lx + ly * ly + lz * lz;

            def = waveReduceSum(def);
            lap = waveReduceSum(lap);
            if ((l & 63) == 0) {
                atomicAdd(&acc[ACC_DEFORM], def);
                atomicAdd(&acc[ACC_LAP], lap);
            }
        }
    }
    __syncthreads();
    if (tid == 0) {
        __threadfence();
        unsigned t = __hip_atomic_fetch_add(doneCnt, 1u, __ATOMIC_ACQ_REL,
                                            __HIP_MEMORY_SCOPE_AGENT);
        if (t == SCAN_BLOCKS - 1) finalize(acc, out);
    }
}

extern "C" void kernel_launch(void* const* d_in, const int* in_sizes, int n_in,
                              void* d_out, int out_size, void* d_ws, size_t ws_size,
                              hipStream_t stream) {
    const float* Y  = (const float*)d_in[0];
    const float* X  = (const float*)d_in[1];
    const float* Rp = (const float*)d_in[2];
    const float* tp = (const float*)d_in[3];
    const float* Rg = (const float*)d_in[4];
    const float* tg = (const float*)d_in[5];
    const float* Xh = (const float*)d_in[6];
    const float* dl = (const float*)d_in[7];
    float* out = (float*)d_out;

    float*    acc     = (float*)d_ws;                            // 14 floats
    unsigned* doneCnt = (unsigned*)((char*)d_ws + 64);
    float4*   YrP     = (float4*)((char*)d_ws + 512);            // 512 KB
    float4*   XP      = YrP + (size_t)BB * NPAD;                 // 512 KB

    hipMemsetAsync(d_ws, 0, 512, stream);
    hipLaunchKernelGGL(k_prep, dim3(BB * NN / 256), dim3(256), 0, stream,
                       Y, X, Rp, tp, Rg, tg, dl, YrP, XP, acc);
    hipLaunchKernelGGL(k_scan, dim3(NN / QG, BB, 2), dim3(512), 0, stream,
                       Xh, XP, YrP, dl, acc, doneCnt, out);
}

// Round 20
// 108.691 us; speedup vs baseline: 1.0942x; 1.0942x over previous
//
#include <hip/hip_runtime.h>
#include <math.h>

#define BB 8
#define NN 4096
#define MM 4000
#define KK 5
#define NWAVE 8
#define QG 128                        // queries per block (2 per lane)
#define CH 256                        // candidates per wave-chunk
#define HSZ 2048                      // candidates staged per half
#define NPAD 4096
#define SCAN_BLOCKS ((NN / QG) * BB * 2)   // 32*8*2 = 512

#define ACC_ROT    0
#define ACC_TRANS  1
#define ACC_ALIGN  2
#define ACC_DISP   3
#define ACC_DEFORM 4
#define ACC_LAP    5
#define ACC_RMSE   6   // 8 entries
#define ACC_COUNT  14

#define INFF __int_as_float(0x7F800000)

__device__ __forceinline__ float waveReduceSum(float v) {
#pragma unroll
    for (int off = 32; off > 0; off >>= 1) v += __shfl_down(v, off, 64);
    return v;
}

// Insert v into sorted (b0<=..<=b4): 1 min + 4 independent med3 (proven r6+).
// Score shifted by -|q|^2 (ranking-invariant). PACK: candidate index in low
// 12 mantissa bits (tie -> smaller index, = top_k semantics).
template<bool SELF, bool PACK>
__device__ __forceinline__ void proc1(float4 c, int midx, int q,
                                      float ca, float cbq, float cc,
                                      float& b0, float& b1, float& b2,
                                      float& b3, float& b4) {
    float sc = fmaf(c.x, ca, fmaf(c.y, cbq, fmaf(c.z, cc, c.w)));
    float v;
    if (PACK) {
        unsigned pk = (__float_as_uint(sc) & 0xFFFFF000u) | (unsigned)midx;
        v = __uint_as_float(pk);
        if (SELF) v = (midx == q) ? INFF : v;
    } else {
        v = sc;
    }
    float n0 = fminf(b0, v);
    float n1 = __builtin_amdgcn_fmed3f(v, b0, b1);
    float n2 = __builtin_amdgcn_fmed3f(v, b1, b2);
    float n3 = __builtin_amdgcn_fmed3f(v, b2, b3);
    float n4 = __builtin_amdgcn_fmed3f(v, b3, b4);
    b0 = n0; b1 = n1; b2 = n2; b3 = n3; b4 = n4;
}

// Scan a CH-candidate LDS chunk (LDS-local base tl, global index base tg) for
// TWO queries per lane. One broadcast ds_read_b128 serves 128 pairs; 4-deep
// A/B ping-pong (r13/r14-proven, no spill).
template<bool SELF, bool PACK>
__device__ __forceinline__ void scanLDS2(const float4* lc, int tl, int tg,
                                         float a0, float b0c, float c0, int q0,
                                         float a1, float b1c, float c1, int q1,
                                         float& x0, float& x1, float& x2,
                                         float& x3, float& x4,
                                         float& y0, float& y1, float& y2,
                                         float& y3, float& y4) {
    float4 A[4], B[4];
#pragma unroll
    for (int j = 0; j < 4; ++j) A[j] = lc[tl + j];

    for (int t0 = 0; t0 < CH; t0 += 8) {
#pragma unroll
        for (int j = 0; j < 4; ++j) B[j] = lc[tl + t0 + 4 + j];
#pragma unroll
        for (int j = 0; j < 4; ++j) {
            proc1<SELF, PACK>(A[j], tg + t0 + j, q0, a0, b0c, c0, x0, x1, x2, x3, x4);
            proc1<SELF, PACK>(A[j], tg + t0 + j, q1, a1, b1c, c1, y0, y1, y2, y3, y4);
        }
        if (t0 + 8 < CH) {
#pragma unroll
            for (int j = 0; j < 4; ++j) A[j] = lc[tl + t0 + 8 + j];
        }
#pragma unroll
        for (int j = 0; j < 4; ++j) {
            proc1<SELF, PACK>(B[j], tg + t0 + 4 + j, q0, a0, b0c, c0, x0, x1, x2, x3, x4);
            proc1<SELF, PACK>(B[j], tg + t0 + 4 + j, q1, a1, b1c, c1, y0, y1, y2, y3, y4);
        }
    }
}

// Merge two sorted 5-lists -> smallest 5, fully static min/max network
// (no runtime-indexed register arrays -> no scratch). u_k = min(A_k, B_k,
// min_{i+j=k-1} max(A_i,B_j)). Ties: equal packed values impossible across
// disjoint index halves; min on equal scores picks smaller packed = smaller
// index, matching top_k.
__device__ __forceinline__ void merge5(float& a0, float& a1, float& a2,
                                       float& a3, float& a4,
                                       float m0, float m1, float m2,
                                       float m3, float m4) {
    float u0 = fminf(a0, m0);
    float u1 = fminf(fminf(a1, m1), fmaxf(a0, m0));
    float u2 = fminf(fminf(a2, m2), fminf(fmaxf(a0, m1), fmaxf(a1, m0)));
    float u3 = fminf(fminf(a3, m3),
                     fminf(fmaxf(a0, m2), fminf(fmaxf(a1, m1), fmaxf(a2, m0))));
    float u4 = fminf(fminf(a4, m4),
                     fminf(fminf(fmaxf(a0, m3), fmaxf(a1, m2)),
                           fminf(fmaxf(a2, m1), fmaxf(a3, m0))));
    a0 = u0; a1 = u1; a2 = u2; a3 = u3; a4 = u4;
}

// K1: Y_rigid (padded float4 + norm), X padded float4 + norm, rmse/disp
// partials, rot/trans losses.
__global__ void k_prep(const float* __restrict__ Y, const float* __restrict__ X,
                       const float* __restrict__ Rp, const float* __restrict__ tp,
                       const float* __restrict__ Rg, const float* __restrict__ tg,
                       const float* __restrict__ dl,
                       float4* __restrict__ YrP, float4* __restrict__ XP,
                       float* __restrict__ acc) {
    int b = blockIdx.x >> 4;
    int n = ((blockIdx.x & 15) << 8) + threadIdx.x;
    size_t base = ((size_t)b * NN + n) * 3;
    float yx = Y[base + 0], yy = Y[base + 1], yz = Y[base + 2];

    float rp[9], rg[9], tpv[3], tgv[3];
#pragma unroll
    for (int i = 0; i < 9; ++i) { rp[i] = Rp[b * 9 + i]; rg[i] = Rg[b * 9 + i]; }
#pragma unroll
    for (int i = 0; i < 3; ++i) { tpv[i] = tp[b * 3 + i]; tgv[i] = tg[b * 3 + i]; }

    float p[3], dr2 = 0.f;
#pragma unroll
    for (int k = 0; k < 3; ++k) {
        float pv = fmaf(yx, rp[k * 3 + 0], fmaf(yy, rp[k * 3 + 1], fmaf(yz, rp[k * 3 + 2], tpv[k])));
        float gv = fmaf(yx, rg[k * 3 + 0], fmaf(yy, rg[k * 3 + 1], fmaf(yz, rg[k * 3 + 2], tgv[k])));
        p[k] = pv;
        float dd = pv - gv;
        dr2 = fmaf(dd, dd, dr2);
    }
    YrP[(size_t)b * NPAD + n] =
        make_float4(p[0], p[1], p[2], fmaf(p[0], p[0], fmaf(p[1], p[1], p[2] * p[2])));

    float4 xe;
    if (n < MM) {
        size_t xb = ((size_t)b * MM + n) * 3;
        float x0 = X[xb + 0], x1 = X[xb + 1], x2 = X[xb + 2];
        xe = make_float4(x0, x1, x2, fmaf(x0, x0, fmaf(x1, x1, x2 * x2)));
    } else {
        xe = make_float4(0.f, 0.f, 0.f, INFF);
    }
    XP[(size_t)b * NPAD + n] = xe;

    float d0 = dl[base + 0], d1 = dl[base + 1], d2 = dl[base + 2];
    float dsq = d0 * d0 + d1 * d1 + d2 * d2;

    dr2 = waveReduceSum(dr2);
    dsq = waveReduceSum(dsq);
    if ((threadIdx.x & 63) == 0) {
        atomicAdd(&acc[ACC_RMSE + b], dr2);
        atomicAdd(&acc[ACC_DISP], dsq);
    }

    if (threadIdx.x == 0 && (blockIdx.x & 15) == 0) {
        float tr = 0.f;
#pragma unroll
        for (int i = 0; i < 9; ++i) tr += rp[i] * rg[i];
        float c = (tr - 1.f) * 0.5f;
        c = fminf(fmaxf(c, -1.f + 1e-7f), 1.f - 1e-7f);
        float dx = tpv[0] - tgv[0], dy = tpv[1] - tgv[1], dz = tpv[2] - tgv[2];
        atomicAdd(&acc[ACC_ROT], acosf(c));
        atomicAdd(&acc[ACC_TRANS], sqrtf(dx * dx + dy * dy + dz * dz));
    }
}

__device__ void finalize(const float* acc, float* out) {
    float a[ACC_COUNT];
#pragma unroll
    for (int i = 0; i < ACC_COUNT; ++i)
        a[i] = __hip_atomic_load(&acc[i], __ATOMIC_RELAXED, __HIP_MEMORY_SCOPE_AGENT);
    float L_rot = a[ACC_ROT] / BB;
    float L_trans = a[ACC_TRANS] / BB;
    float L_rmse = 0.f;
#pragma unroll
    for (int b = 0; b < BB; ++b) L_rmse += sqrtf(a[ACC_RMSE + b] / NN);
    L_rmse /= BB;
    float L_align = a[ACC_ALIGN] / ((float)BB * NN * KK);
    float L_disp = a[ACC_DISP] / ((float)BB * NN);
    float L_def = a[ACC_DEFORM] / ((float)BB * NN * KK);
    float L_lap = a[ACC_LAP] / ((float)BB * NN);
    float rigid = L_rot + L_trans + L_rmse;
    float nr = L_align + 0.01f * L_disp + 0.1f * L_def + 0.1f * L_lap;
    out[0] = rigid + nr; out[1] = rigid; out[2] = nr;
    out[3] = L_rot; out[4] = L_trans; out[5] = L_rmse;
    out[6] = L_align; out[7] = L_disp; out[8] = L_def; out[9] = L_lap;
}

#define MERGE_STEP(W) { float d = md[W][l][pp##W]; if (d < best) { best = d; bw = W; } }
#define MERGE_ADV()  { pp0 += (bw == 0); pp1 += (bw == 1); pp2 += (bw == 2); pp3 += (bw == 3); \
                       pp4 += (bw == 4); pp5 += (bw == 5); pp6 += (bw == 6); pp7 += (bw == 7); }

// K2: fully fused scan (r14, session best: 108.05 us, absmax 0.0).
// blockIdx.z = mode (0=align on XP, 1=knn on YrP). Loop over 2 halves:
// stage 2048 cands (32 KB), 8 waves x 256-chunks, Q=2; per-half 8-way LDS
// merge -> static merge5 accumulation in registers; epilogue + last-block
// finalize in-block. No partials, no merge kernel.
__global__ __launch_bounds__(512, 4) void k_scan(const float* __restrict__ Xh,
                                                 const float4* __restrict__ XP,
                                                 const float4* __restrict__ YrP,
                                                 const float* __restrict__ dl,
                                                 float* __restrict__ acc,
                                                 unsigned* __restrict__ doneCnt,
                                                 float* __restrict__ out) {
    __shared__ float4 stage[HSZ];                  // 32 KB candidate stage
    __shared__ float md[NWAVE][QG][6];             // 24 KB merge partials
    int tid = threadIdx.x, wave = tid >> 6, lane = tid & 63;
    int qg = blockIdx.x, b = blockIdx.y, mode = blockIdx.z;
    int q0 = qg * QG + lane, q1 = q0 + 64;

    const float4* cbG = (mode == 0 ? XP : YrP) + (size_t)b * NPAD;

    float qx0, qy0, qz0, qx1, qy1, qz1;
    if (mode == 0) {
        size_t a0 = ((size_t)b * NN + q0) * 3;
        size_t a1 = ((size_t)b * NN + q1) * 3;
        qx0 = Xh[a0 + 0]; qy0 = Xh[a0 + 1]; qz0 = Xh[a0 + 2];
        qx1 = Xh[a1 + 0]; qy1 = Xh[a1 + 1]; qz1 = Xh[a1 + 2];
    } else {
        float4 p0 = cbG[q0], p1 = cbG[q1];
        qx0 = p0.x; qy0 = p0.y; qz0 = p0.z;
        qx1 = p1.x; qy1 = p1.y; qz1 = p1.z;
    }

    float f0 = INFF, f1 = INFF, f2 = INFF, f3 = INFF, f4 = INFF;  // running top-5

#pragma unroll
    for (int half = 0; half < 2; ++half) {
        __syncthreads();                           // md reads of prev half done
#pragma unroll
        for (int i = 0; i < HSZ / 512; ++i)
            stage[tid + i * 512] = cbG[half * HSZ + tid + i * 512];
        __syncthreads();

        float x0 = INFF, x1 = INFF, x2 = INFF, x3 = INFF, x4 = INFF;
        float y0 = INFF, y1 = INFF, y2 = INFF, y3 = INFF, y4 = INFF;
        int tl = wave * CH;
        int tg = half * HSZ + tl;
        bool hasSelf = (mode == 1) && (half == (qg >> 4)) && (wave == ((qg >> 1) & 7));
        if (mode == 0) {
            scanLDS2<false, false>(stage, tl, tg,
                                   -2.f * qx0, -2.f * qy0, -2.f * qz0, 0,
                                   -2.f * qx1, -2.f * qy1, -2.f * qz1, 0,
                                   x0, x1, x2, x3, x4, y0, y1, y2, y3, y4);
        } else if (hasSelf) {
            scanLDS2<true, true>(stage, tl, tg,
                                 -2.f * qx0, -2.f * qy0, -2.f * qz0, q0,
                                 -2.f * qx1, -2.f * qy1, -2.f * qz1, q1,
                                 x0, x1, x2, x3, x4, y0, y1, y2, y3, y4);
        } else {
            scanLDS2<false, true>(stage, tl, tg,
                                  -2.f * qx0, -2.f * qy0, -2.f * qz0, q0,
                                  -2.f * qx1, -2.f * qy1, -2.f * qz1, q1,
                                  x0, x1, x2, x3, x4, y0, y1, y2, y3, y4);
        }

        md[wave][lane][0] = x0; md[wave][lane][1] = x1; md[wave][lane][2] = x2;
        md[wave][lane][3] = x3; md[wave][lane][4] = x4; md[wave][lane][5] = INFF;
        md[wave][lane + 64][0] = y0; md[wave][lane + 64][1] = y1;
        md[wave][lane + 64][2] = y2; md[wave][lane + 64][3] = y3;
        md[wave][lane + 64][4] = y4; md[wave][lane + 64][5] = INFF;
        __syncthreads();

        if (tid < QG) {
            int l = tid;
            int pp0 = 0, pp1 = 0, pp2 = 0, pp3 = 0, pp4 = 0, pp5 = 0, pp6 = 0, pp7 = 0;
            float m5[KK];
#pragma unroll
            for (int k = 0; k < KK; ++k) {
                float best = INFF; int bw = 0;
                MERGE_STEP(0) MERGE_STEP(1) MERGE_STEP(2) MERGE_STEP(3)
                MERGE_STEP(4) MERGE_STEP(5) MERGE_STEP(6) MERGE_STEP(7)
                m5[k] = best;
                MERGE_ADV()
            }
            merge5(f0, f1, f2, f3, f4, m5[0], m5[1], m5[2], m5[3], m5[4]);
        }
    }

    // ---- epilogue (tid < QG owns query q) ----
    if (tid < QG) {
        int l = tid;
        int q = qg * QG + l;
        if (mode == 0) {
            size_t a0 = ((size_t)b * NN + q) * 3;
            float qx = Xh[a0 + 0], qy = Xh[a0 + 1], qz = Xh[a0 + 2];
            float qn = fmaf(qx, qx, fmaf(qy, qy, qz * qz));
            float s = fmaxf(f0 + qn, 0.f) + fmaxf(f1 + qn, 0.f) + fmaxf(f2 + qn, 0.f)
                    + fmaxf(f3 + qn, 0.f) + fmaxf(f4 + qn, 0.f);
            s = waveReduceSum(s);
            if ((l & 63) == 0) atomicAdd(&acc[ACC_ALIGN], s);
        } else {
            int si[KK];
            si[0] = (int)(__float_as_uint(f0) & 0xFFFu);
            si[1] = (int)(__float_as_uint(f1) & 0xFFFu);
            si[2] = (int)(__float_as_uint(f2) & 0xFFFu);
            si[3] = (int)(__float_as_uint(f3) & 0xFFFu);
            si[4] = (int)(__float_as_uint(f4) & 0xFFFu);

            float4 qp = cbG[q];
            const float* xh = Xh + (size_t)b * NN * 3;
            const float* dlb = dl + (size_t)b * NN * 3;
            float xnx = xh[q * 3 + 0], xny = xh[q * 3 + 1], xnz = xh[q * 3 + 2];
            float dnx = dlb[q * 3 + 0], dny = dlb[q * 3 + 1], dnz = dlb[q * 3 + 2];

            float def = 0.f, sx = 0.f, sy = 0.f, sz = 0.f;
#pragma unroll
            for (int k = 0; k < KK; ++k) {
                int n = si[k];
                float4 yj = cbG[n];                // L2-resident gather
                float ex = (xh[n * 3 + 0] - xnx) - (yj.x - qp.x);
                float ey = (xh[n * 3 + 1] - xny) - (yj.y - qp.y);
                float ez = (xh[n * 3 + 2] - xnz) - (yj.z - qp.z);
                def += ex * ex + ey * ey + ez * ez;
                sx += dlb[n * 3 + 0]; sy += dlb[n * 3 + 1]; sz += dlb[n * 3 + 2];
            }
            float lx = dnx - sx / 5.f, ly = dny - sy / 5.f, lz = dnz - sz / 5.f;
            float lap = lx * lx + ly * ly + lz * lz;

            def = waveReduceSum(def);
            lap = waveReduceSum(lap);
            if ((l & 63) == 0) {
                atomicAdd(&acc[ACC_DEFORM], def);
                atomicAdd(&acc[ACC_LAP], lap);
            }
        }
    }
    __syncthreads();
    if (tid == 0) {
        __threadfence();
        unsigned t = __hip_atomic_fetch_add(doneCnt, 1u, __ATOMIC_ACQ_REL,
                                            __HIP_MEMORY_SCOPE_AGENT);
        if (t == SCAN_BLOCKS - 1) finalize(acc, out);
    }
}

extern "C" void kernel_launch(void* const* d_in, const int* in_sizes, int n_in,
                              void* d_out, int out_size, void* d_ws, size_t ws_size,
                              hipStream_t stream) {
    const float* Y  = (const float*)d_in[0];
    const float* X  = (const float*)d_in[1];
    const float* Rp = (const float*)d_in[2];
    const float* tp = (const float*)d_in[3];
    const float* Rg = (const float*)d_in[4];
    const float* tg = (const float*)d_in[5];
    const float* Xh = (const float*)d_in[6];
    const float* dl = (const float*)d_in[7];
    float* out = (float*)d_out;

    float*    acc     = (float*)d_ws;                            // 14 floats
    unsigned* doneCnt = (unsigned*)((char*)d_ws + 64);
    float4*   YrP     = (float4*)((char*)d_ws + 512);            // 512 KB
    float4*   XP      = YrP + (size_t)BB * NPAD;                 // 512 KB

    hipMemsetAsync(d_ws, 0, 512, stream);
    hipLaunchKernelGGL(k_prep, dim3(BB * NN / 256), dim3(256), 0, stream,
                       Y, X, Rp, tp, Rg, tg, dl, YrP, XP, acc);
    hipLaunchKernelGGL(k_scan, dim3(NN / QG, BB, 2), dim3(512), 0, stream,
                       Xh, XP, YrP, dl, acc, doneCnt, out);
}